// Round 15
// baseline (46.595 us; speedup 1.0000x reference)
//
#include <hip/hip_runtime.h>
#include <math.h>

#define HW_   6688      // 44*152
#define W_    152
#define NPIX  107008    // 16*44*152
#define OW_   1216      // 152*8
#define OHW_  428032    // 352*1216

typedef _Float16 f16;
typedef _Float16 f16x2 __attribute__((ext_vector_type(2)));
typedef _Float16 f16x4 __attribute__((ext_vector_type(4)));
typedef _Float16 f16x8 __attribute__((ext_vector_type(8)));
typedef float    f32x4 __attribute__((ext_vector_type(4)));

#define MFMA(a,b,c) __builtin_amdgcn_mfma_f32_16x16x32_f16((a),(b),(c),0,0,0)

// ---- LDS layout (f16 units), 64 pixels/block. x staged in TWO 64-channel
// halves into [64][72]; a1/a2/a3 overlay the x region AFTER the last block
// barrier (x dead; per-wave rows disjoint -> wave fences suffice in phase C).
#define SXH_STR  72             // x-half [64][72] at 0 -> 4608 f16
#define SA1_OFF  0              // a1 [64][40] -> 2560
#define SA1_STR  40
#define SA2_OFF  2560           // a2 [64][24] -> ends 4096
#define SA2_STR  24
#define SA3_OFF  4096           // a3 [64][16] -> ends 5120
#define SA3_STR  16
#define SA0_OFF  5120           // a0 [64][72] -> ends 9728
#define SA0_STR  72
#define LDSF16   9728           // 19456 B -> 8 blocks/CU (155.6 KB of 160)

__device__ __forceinline__ float fast_sigmoid(float v) {
    return __builtin_amdgcn_rcpf(1.0f + __expf(-v));
}
__device__ __forceinline__ float eluf(float v) {
    return v > 0.0f ? v : (__expf(v) - 1.0f);
}
// split fp32 -> fp16 hi + fp16 lo (w ~= hi + lo)
__device__ __forceinline__ void split8(const float* v, f16x8& hi, f16x8& lo) {
#pragma unroll
    for (int e = 0; e < 8; ++e) {
        f16 h = (f16)v[e];
        hi[e] = h;
        lo[e] = (f16)(v[e] - (float)h);
    }
}
__device__ __forceinline__ f16x4 elu_cvt4(f32x4 a) {
    f16x4 r;
    r[0] = (f16)eluf(a[0]); r[1] = (f16)eluf(a[1]);
    r[2] = (f16)eluf(a[2]); r[3] = (f16)eluf(a[3]);
    return r;
}
// Intra-wave LDS handoff fence (cross-wave safety = disjoint rows/regions).
__device__ __forceinline__ void wave_fence() {
    __builtin_amdgcn_sched_barrier(0);
    __builtin_amdgcn_wave_barrier();
    __builtin_amdgcn_sched_barrier(0);
}

// 256 threads = 4 waves, 64 pixels/block, 8 blocks/CU (32 waves = full slots).
// L0: wave wv computes channels [wv*16,+16) for all 4 pixel tiles (x via LDS).
// Phase C: wave wv owns pixel tile [wv*16,+16) end-to-end, fence-only.
__global__ __launch_bounds__(256, 8)
void lpg_mfma(const float* __restrict__ x,
              const float* __restrict__ w0, const float* __restrict__ b0,
              const float* __restrict__ w1, const float* __restrict__ b1,
              const float* __restrict__ w2, const float* __restrict__ b2,
              const float* __restrict__ w3, const float* __restrict__ b3,
              const float* __restrict__ w4, const float* __restrict__ b4,
              const float* __restrict__ cw, const float* __restrict__ cb,
              float* __restrict__ out) {
    __shared__ __align__(16) f16 S[LDSF16];

    const int tid  = threadIdx.x;
    const int wv   = __builtin_amdgcn_readfirstlane(tid >> 6);
    const int lane = tid & 63;
    const int p    = lane & 15;   // MFMA row/col index
    const int q    = lane >> 4;   // k-group / C-row group
    const int pixbase = blockIdx.x * 64;

    // staging: thread (i = tid&63) stages pixel i, 16 channels per half
    const int i    = tid & 63;
    const int csub = (tid >> 6) * 16;          // 0..48 within the 64-ch half
    int pixs = pixbase + i;
    int bbs  = pixs / HW_;
    int hws  = pixs - bbs * HW_;
    const float* xps = x + ((size_t)bbs * 128 + csub) * HW_ + hws;
    f16* dsts = S + i * SXH_STR + csub;

    // ---- stage half 0 (channels 0..63): coalesced 256B wave requests
#pragma unroll 8
    for (int k = 0; k < 16; k += 2) {
        float v0 = xps[(size_t)k * HW_];
        float v1 = xps[(size_t)(k + 1) * HW_];
        auto pk = __builtin_amdgcn_cvt_pkrtz(v0, v1);
        f16x2 h; h[0] = (f16)pk[0]; h[1] = (f16)pk[1];
        *(f16x2*)(dsts + k) = h;
    }

    // ---- layer-0 weights for k-half 0 + bias; accs for 4 pixel tiles
    const int w0row = (wv * 16 + p) * 128 + q * 8;
    f16x8 w0h[2], w0l[2];
#pragma unroll
    for (int kt = 0; kt < 2; ++kt) {
        float v[8];
#pragma unroll
        for (int e = 0; e < 8; ++e) v[e] = w0[w0row + kt * 32 + e];
        split8(v, w0h[kt], w0l[kt]);
    }
    f32x4 acc[4];
    {
        f32x4 b0v = *(const f32x4*)(b0 + wv * 16 + 4 * q);
#pragma unroll
        for (int t = 0; t < 4; ++t) acc[t] = b0v;
    }
    __syncthreads();   // (1) half 0 staged

#pragma unroll 2
    for (int t = 0; t < 4; ++t) {
        const f16* bp = S + (t * 16 + p) * SXH_STR + q * 8;
        f16x8 bf0 = *(const f16x8*)(bp);
        f16x8 bf1 = *(const f16x8*)(bp + 32);
        acc[t] = MFMA(w0h[0], bf0, acc[t]); acc[t] = MFMA(w0l[0], bf0, acc[t]);
        acc[t] = MFMA(w0h[1], bf1, acc[t]); acc[t] = MFMA(w0l[1], bf1, acc[t]);
    }
    __syncthreads();   // (2) all waves done reading half 0

    // ---- stage half 1 (channels 64..127) over the same buffer
#pragma unroll 8
    for (int k = 0; k < 16; k += 2) {
        float v0 = xps[(size_t)(k + 64) * HW_];
        float v1 = xps[(size_t)(k + 65) * HW_];
        auto pk = __builtin_amdgcn_cvt_pkrtz(v0, v1);
        f16x2 h; h[0] = (f16)pk[0]; h[1] = (f16)pk[1];
        *(f16x2*)(dsts + k) = h;
    }
#pragma unroll
    for (int kt = 0; kt < 2; ++kt) {     // w0 k-half 1 (reuses registers)
        float v[8];
#pragma unroll
        for (int e = 0; e < 8; ++e) v[e] = w0[w0row + 64 + kt * 32 + e];
        split8(v, w0h[kt], w0l[kt]);
    }
    __syncthreads();   // (3) half 1 staged

#pragma unroll 2
    for (int t = 0; t < 4; ++t) {
        const f16* bp = S + (t * 16 + p) * SXH_STR + q * 8;
        f16x8 bf0 = *(const f16x8*)(bp);
        f16x8 bf1 = *(const f16x8*)(bp + 32);
        acc[t] = MFMA(w0h[0], bf0, acc[t]); acc[t] = MFMA(w0l[0], bf0, acc[t]);
        acc[t] = MFMA(w0h[1], bf1, acc[t]); acc[t] = MFMA(w0l[1], bf1, acc[t]);
        *(f16x4*)(S + SA0_OFF + (t * 16 + p) * SA0_STR + wv * 16 + 4 * q) = elu_cvt4(acc[t]);
    }
    __syncthreads();   // (4) a0 complete — last block barrier; x region dead

    // ================= phase C: wave-private tile [wv*16,+16) =================
    f16x8 w1h[2][2], w1l[2][2];
#pragma unroll
    for (int Mt = 0; Mt < 2; ++Mt)
#pragma unroll
        for (int kt = 0; kt < 2; ++kt) {
            float v[8];
#pragma unroll
            for (int e = 0; e < 8; ++e) v[e] = w1[(Mt * 16 + p) * 64 + kt * 32 + q * 8 + e];
            split8(v, w1h[Mt][kt], w1l[Mt][kt]);
        }
    f16x8 w2h, w2l;
    {
        float v[8];
#pragma unroll
        for (int e = 0; e < 8; ++e) v[e] = w2[p * 32 + q * 8 + e];
        split8(v, w2h, w2l);
    }
    f16x8 w3h, w3l;
    {
        float v[8];
        bool ok = (p < 8) && (q < 2);
#pragma unroll
        for (int e = 0; e < 8; ++e) v[e] = ok ? w3[p * 16 + q * 8 + e] : 0.0f;
        split8(v, w3h, w3l);
    }
    f16x8 w4h, w4l;
    {
        float v[8];
        bool ok = (p < 4) && (q == 0);
#pragma unroll
        for (int e = 0; e < 8; ++e) v[e] = ok ? w4[p * 8 + e] : 0.0f;
        split8(v, w4h, w4l);
    }
    f16x8 whh, whl;
    {
        float v[8];
        bool ok = (p < 3) && (q == 0);
#pragma unroll
        for (int e = 0; e < 8; ++e) v[e] = (ok && e < 4) ? cw[p * 4 + e] : 0.0f;
        split8(v, whh, whl);
    }
    const f32x4 z4 = {0.f, 0.f, 0.f, 0.f};
    f32x4 b1v0 = *(const f32x4*)(b1 + 4 * q);
    f32x4 b1v1 = *(const f32x4*)(b1 + 16 + 4 * q);
    f32x4 b2v  = *(const f32x4*)(b2 + 4 * q);
    f32x4 b3v  = *(const f32x4*)(b3 + (q & 1) * 4);
    f32x4 b4v  = *(const f32x4*)(b4);
    float cb0v = cb[0], cb1v = cb[1], cb2v = cb[2];

    const int i0 = wv * 16 + p;   // this wave's tile row (block-local pixel)

    // ---- layer 1: 64 -> 32
    {
        f32x4 c0 = b1v0, c1 = b1v1;
#pragma unroll
        for (int kt = 0; kt < 2; ++kt) {
            f16x8 bf = *(const f16x8*)(S + SA0_OFF + i0 * SA0_STR + kt * 32 + q * 8);
            c0 = MFMA(w1h[0][kt], bf, c0); c0 = MFMA(w1l[0][kt], bf, c0);
            c1 = MFMA(w1h[1][kt], bf, c1); c1 = MFMA(w1l[1][kt], bf, c1);
        }
        *(f16x4*)(S + SA1_OFF + i0 * SA1_STR + 4 * q)      = elu_cvt4(c0);
        *(f16x4*)(S + SA1_OFF + i0 * SA1_STR + 16 + 4 * q) = elu_cvt4(c1);
    }
    wave_fence();   // a1 handoff (intra-wave cross-lane)

    // ---- layer 2: 32 -> 16
    {
        f16x8 bf = *(const f16x8*)(S + SA1_OFF + i0 * SA1_STR + q * 8);
        f32x4 c = b2v;
        c = MFMA(w2h, bf, c); c = MFMA(w2l, bf, c);
        *(f16x4*)(S + SA2_OFF + i0 * SA2_STR + 4 * q) = elu_cvt4(c);
    }
    wave_fence();   // a2 handoff

    // ---- layer 3: 16 -> 8 (K valid for q<2)
    {
        f16x8 bf = *(const f16x8*)(S + SA2_OFF + i0 * SA2_STR + (q & 1) * 8);
        if (q >= 2) bf = (f16x8){};
        f32x4 c = (q < 2) ? b3v : z4;
        c = MFMA(w3h, bf, c); c = MFMA(w3l, bf, c);
        if (q < 2) *(f16x4*)(S + SA3_OFF + i0 * SA3_STR + 4 * q) = elu_cvt4(c);
    }
    wave_fence();   // a3 handoff

    // ---- layer 4 (8->4) + head (4->3): a4 stays in registers
    f32x4 cy;
    {
        f16x8 bf = *(const f16x8*)(S + SA3_OFF + i0 * SA3_STR);
        if (q != 0) bf = (f16x8){};
        f32x4 c = (q == 0) ? b4v : z4;
        c = MFMA(w4h, bf, c); c = MFMA(w4l, bf, c);

        f16x8 h = (f16x8){};
        if (q == 0) {
#pragma unroll
            for (int e = 0; e < 4; ++e) h[e] = (f16)eluf(c[e]);
        }
        cy = z4;
        if (q == 0) { cy[0] = cb0v; cy[1] = cb1v; cy[2] = cb2v; }
        cy = MFMA(whh, h, cy); cy = MFMA(whl, h, cy);
    }

    // ---- epilogue: y via shuffle from the q==0 lane of column p ----
    {
        float y0 = __shfl(cy[0], p);
        float y1 = __shfl(cy[1], p);
        float y2 = __shfl(cy[2], p);

        float theta = 0.5235987756f * fast_sigmoid(y0);   // pi/6
        float phi   = 6.2831853072f * fast_sigmoid(y1);   // 2*pi
        float dist  = 83.0f         * fast_sigmoid(y2);
        float st = __sinf(theta), ct = __cosf(theta);
        float sp = __sinf(phi),   cp = __cosf(phi);
        float n1 = st * cp, n2 = st * sp, n3 = ct;
        float inv = __frsqrt_rn(fmaf(n1, n1, fmaf(n2, n2, n3 * n3)));
        n1 *= inv; n2 *= inv; n3 *= inv;

        const float ksc = 1.0f / (8.0f * 715.0f);
        float nu[8];
#pragma unroll
        for (int j = 0; j < 8; ++j) nu[j] = n1 * (((float)j - 3.5f) * ksc);

        int pix = pixbase + i0;
        int bb  = pix / HW_;
        int hw  = pix - bb * HW_;
        int hh  = hw / W_;
        int ww  = hw - hh * W_;
        const int obase = bb * OHW_ + (hh * 8) * OW_ + ww * 8;
#pragma unroll
        for (int r = 0; r < 2; ++r) {
            int irow = q * 2 + r;               // lane (p,q) writes rows 2q,2q+1
            float base = fmaf(n2, ((float)irow - 3.5f) * ksc, n3);
            float4 r0, r1;
            r0.x = dist * __builtin_amdgcn_rcpf(base + nu[0]);
            r0.y = dist * __builtin_amdgcn_rcpf(base + nu[1]);
            r0.z = dist * __builtin_amdgcn_rcpf(base + nu[2]);
            r0.w = dist * __builtin_amdgcn_rcpf(base + nu[3]);
            r1.x = dist * __builtin_amdgcn_rcpf(base + nu[4]);
            r1.y = dist * __builtin_amdgcn_rcpf(base + nu[5]);
            r1.z = dist * __builtin_amdgcn_rcpf(base + nu[6]);
            r1.w = dist * __builtin_amdgcn_rcpf(base + nu[7]);
            float4* op = (float4*)(out + obase + irow * OW_);
            op[0] = r0;
            op[1] = r1;
        }
    }
}

extern "C" void kernel_launch(void* const* d_in, const int* in_sizes, int n_in,
                              void* d_out, int out_size, void* d_ws, size_t ws_size,
                              hipStream_t stream) {
    const float* x  = (const float*)d_in[0];
    const float* w0 = (const float*)d_in[1];
    const float* b0 = (const float*)d_in[2];
    const float* w1 = (const float*)d_in[3];
    const float* b1 = (const float*)d_in[4];
    const float* w2 = (const float*)d_in[5];
    const float* b2 = (const float*)d_in[6];
    const float* w3 = (const float*)d_in[7];
    const float* b3 = (const float*)d_in[8];
    const float* w4 = (const float*)d_in[9];
    const float* b4 = (const float*)d_in[10];
    const float* cw = (const float*)d_in[11];
    const float* cb = (const float*)d_in[12];
    float* outp = (float*)d_out;

    lpg_mfma<<<NPIX / 64, 256, 0, stream>>>(x, w0, b0, w1, b1, w2, b2, w3, b3,
                                            w4, b4, cw, cb, outp);
}

// Round 16
// 39.451 us; speedup vs baseline: 1.1811x; 1.1811x over previous
//
#include <hip/hip_runtime.h>
#include <math.h>

#define HW_   6688      // 44*152
#define W_    152
#define NPIX  107008    // 16*44*152
#define OW_   1216      // 152*8
#define OHW_  428032    // 352*1216

typedef _Float16 f16;
typedef _Float16 f16x2 __attribute__((ext_vector_type(2)));
typedef _Float16 f16x4 __attribute__((ext_vector_type(4)));
typedef _Float16 f16x8 __attribute__((ext_vector_type(8)));
typedef float    f32x4 __attribute__((ext_vector_type(4)));

#define MFMA(a,b,c) __builtin_amdgcn_mfma_f32_16x16x32_f16((a),(b),(c),0,0,0)

// ---- LDS layout (f16 units), 64 pixels/block. x staged in TWO 64-channel
// halves into [64][72]; a1/a2/a3 overlay the x region AFTER the last block
// barrier (x dead; per-wave rows disjoint -> wave fences suffice in phase C).
#define SXH_STR  72             // x-half [64][72] at 0 -> 4608 f16
#define SA1_OFF  0              // a1 [64][40] -> 2560
#define SA1_STR  40
#define SA2_OFF  2560           // a2 [64][24] -> ends 4096
#define SA2_STR  24
#define SA3_OFF  4096           // a3 [64][16] -> ends 5120
#define SA3_STR  16
#define SA0_OFF  5120           // a0 [64][72] -> ends 9728
#define SA0_STR  72
#define LDSF16   9728           // 19456 B

__device__ __forceinline__ float fast_sigmoid(float v) {
    return __builtin_amdgcn_rcpf(1.0f + __expf(-v));
}
__device__ __forceinline__ float eluf(float v) {
    return v > 0.0f ? v : (__expf(v) - 1.0f);
}
// split fp32 -> fp16 hi + fp16 lo (w ~= hi + lo)
__device__ __forceinline__ void split8(const float* v, f16x8& hi, f16x8& lo) {
#pragma unroll
    for (int e = 0; e < 8; ++e) {
        f16 h = (f16)v[e];
        hi[e] = h;
        lo[e] = (f16)(v[e] - (float)h);
    }
}
__device__ __forceinline__ f16x4 elu_cvt4(f32x4 a) {
    f16x4 r;
    r[0] = (f16)eluf(a[0]); r[1] = (f16)eluf(a[1]);
    r[2] = (f16)eluf(a[2]); r[3] = (f16)eluf(a[3]);
    return r;
}
// Intra-wave LDS handoff fence (cross-wave safety = disjoint rows/regions).
__device__ __forceinline__ void wave_fence() {
    __builtin_amdgcn_sched_barrier(0);
    __builtin_amdgcn_wave_barrier();
    __builtin_amdgcn_sched_barrier(0);
}

// 256 threads = 4 waves, 64 pixels/block, 6 blocks/CU (VGPR-limited; r15's
// 8 blocks/CU forced a 64-VGPR cap -> massive scratch spill, WRITE_SIZE 3x).
// L0: wave wv computes channels [wv*16,+16) for all 4 pixel tiles (x via LDS).
// Phase C: wave wv owns pixel tile [wv*16,+16) end-to-end, fence-only.
__global__ __launch_bounds__(256, 6)
void lpg_mfma(const float* __restrict__ x,
              const float* __restrict__ w0, const float* __restrict__ b0,
              const float* __restrict__ w1, const float* __restrict__ b1,
              const float* __restrict__ w2, const float* __restrict__ b2,
              const float* __restrict__ w3, const float* __restrict__ b3,
              const float* __restrict__ w4, const float* __restrict__ b4,
              const float* __restrict__ cw, const float* __restrict__ cb,
              float* __restrict__ out) {
    __shared__ __align__(16) f16 S[LDSF16];

    const int tid  = threadIdx.x;
    const int wv   = __builtin_amdgcn_readfirstlane(tid >> 6);
    const int lane = tid & 63;
    const int p    = lane & 15;   // MFMA row/col index
    const int q    = lane >> 4;   // k-group / C-row group
    const int pixbase = blockIdx.x * 64;

    // staging: thread (i = tid&63) stages pixel i, 16 channels per half
    const int i    = tid & 63;
    const int csub = (tid >> 6) * 16;          // 0..48 within the 64-ch half
    int pixs = pixbase + i;
    int bbs  = pixs / HW_;
    int hws  = pixs - bbs * HW_;
    const float* xps = x + ((size_t)bbs * 128 + csub) * HW_ + hws;
    f16* dsts = S + i * SXH_STR + csub;

    // ---- stage half 0 (channels 0..63): coalesced 256B wave requests
#pragma unroll 8
    for (int k = 0; k < 16; k += 2) {
        float v0 = xps[(size_t)k * HW_];
        float v1 = xps[(size_t)(k + 1) * HW_];
        auto pk = __builtin_amdgcn_cvt_pkrtz(v0, v1);
        f16x2 h; h[0] = (f16)pk[0]; h[1] = (f16)pk[1];
        *(f16x2*)(dsts + k) = h;
    }

    // ---- layer-0 weights for k-half 0 + bias; accs for 4 pixel tiles
    const int w0row = (wv * 16 + p) * 128 + q * 8;
    f16x8 w0h[2], w0l[2];
#pragma unroll
    for (int kt = 0; kt < 2; ++kt) {
        float v[8];
#pragma unroll
        for (int e = 0; e < 8; ++e) v[e] = w0[w0row + kt * 32 + e];
        split8(v, w0h[kt], w0l[kt]);
    }
    f32x4 acc[4];
    {
        f32x4 b0v = *(const f32x4*)(b0 + wv * 16 + 4 * q);
#pragma unroll
        for (int t = 0; t < 4; ++t) acc[t] = b0v;
    }
    __syncthreads();   // (1) half 0 staged

#pragma unroll 2
    for (int t = 0; t < 4; ++t) {
        const f16* bp = S + (t * 16 + p) * SXH_STR + q * 8;
        f16x8 bf0 = *(const f16x8*)(bp);
        f16x8 bf1 = *(const f16x8*)(bp + 32);
        acc[t] = MFMA(w0h[0], bf0, acc[t]); acc[t] = MFMA(w0l[0], bf0, acc[t]);
        acc[t] = MFMA(w0h[1], bf1, acc[t]); acc[t] = MFMA(w0l[1], bf1, acc[t]);
    }
    __syncthreads();   // (2) all waves done reading half 0

    // ---- stage half 1 (channels 64..127) over the same buffer
#pragma unroll 8
    for (int k = 0; k < 16; k += 2) {
        float v0 = xps[(size_t)(k + 64) * HW_];
        float v1 = xps[(size_t)(k + 65) * HW_];
        auto pk = __builtin_amdgcn_cvt_pkrtz(v0, v1);
        f16x2 h; h[0] = (f16)pk[0]; h[1] = (f16)pk[1];
        *(f16x2*)(dsts + k) = h;
    }
#pragma unroll
    for (int kt = 0; kt < 2; ++kt) {     // w0 k-half 1 (reuses registers)
        float v[8];
#pragma unroll
        for (int e = 0; e < 8; ++e) v[e] = w0[w0row + 64 + kt * 32 + e];
        split8(v, w0h[kt], w0l[kt]);
    }
    __syncthreads();   // (3) half 1 staged

#pragma unroll 2
    for (int t = 0; t < 4; ++t) {
        const f16* bp = S + (t * 16 + p) * SXH_STR + q * 8;
        f16x8 bf0 = *(const f16x8*)(bp);
        f16x8 bf1 = *(const f16x8*)(bp + 32);
        acc[t] = MFMA(w0h[0], bf0, acc[t]); acc[t] = MFMA(w0l[0], bf0, acc[t]);
        acc[t] = MFMA(w0h[1], bf1, acc[t]); acc[t] = MFMA(w0l[1], bf1, acc[t]);
        *(f16x4*)(S + SA0_OFF + (t * 16 + p) * SA0_STR + wv * 16 + 4 * q) = elu_cvt4(acc[t]);
    }
    __syncthreads();   // (4) a0 complete — last block barrier; x region dead

    // ================= phase C: wave-private tile [wv*16,+16) =================
    f16x8 w1h[2][2], w1l[2][2];
#pragma unroll
    for (int Mt = 0; Mt < 2; ++Mt)
#pragma unroll
        for (int kt = 0; kt < 2; ++kt) {
            float v[8];
#pragma unroll
            for (int e = 0; e < 8; ++e) v[e] = w1[(Mt * 16 + p) * 64 + kt * 32 + q * 8 + e];
            split8(v, w1h[Mt][kt], w1l[Mt][kt]);
        }
    f16x8 w2h, w2l;
    {
        float v[8];
#pragma unroll
        for (int e = 0; e < 8; ++e) v[e] = w2[p * 32 + q * 8 + e];
        split8(v, w2h, w2l);
    }
    f16x8 w3h, w3l;
    {
        float v[8];
        bool ok = (p < 8) && (q < 2);
#pragma unroll
        for (int e = 0; e < 8; ++e) v[e] = ok ? w3[p * 16 + q * 8 + e] : 0.0f;
        split8(v, w3h, w3l);
    }
    f16x8 w4h, w4l;
    {
        float v[8];
        bool ok = (p < 4) && (q == 0);
#pragma unroll
        for (int e = 0; e < 8; ++e) v[e] = ok ? w4[p * 8 + e] : 0.0f;
        split8(v, w4h, w4l);
    }
    f16x8 whh, whl;
    {
        float v[8];
        bool ok = (p < 3) && (q == 0);
#pragma unroll
        for (int e = 0; e < 8; ++e) v[e] = (ok && e < 4) ? cw[p * 4 + e] : 0.0f;
        split8(v, whh, whl);
    }
    const f32x4 z4 = {0.f, 0.f, 0.f, 0.f};
    f32x4 b1v0 = *(const f32x4*)(b1 + 4 * q);
    f32x4 b1v1 = *(const f32x4*)(b1 + 16 + 4 * q);
    f32x4 b2v  = *(const f32x4*)(b2 + 4 * q);
    f32x4 b3v  = *(const f32x4*)(b3 + (q & 1) * 4);
    f32x4 b4v  = *(const f32x4*)(b4);
    float cb0v = cb[0], cb1v = cb[1], cb2v = cb[2];

    const int i0 = wv * 16 + p;   // this wave's tile row (block-local pixel)

    // ---- layer 1: 64 -> 32
    {
        f32x4 c0 = b1v0, c1 = b1v1;
#pragma unroll
        for (int kt = 0; kt < 2; ++kt) {
            f16x8 bf = *(const f16x8*)(S + SA0_OFF + i0 * SA0_STR + kt * 32 + q * 8);
            c0 = MFMA(w1h[0][kt], bf, c0); c0 = MFMA(w1l[0][kt], bf, c0);
            c1 = MFMA(w1h[1][kt], bf, c1); c1 = MFMA(w1l[1][kt], bf, c1);
        }
        *(f16x4*)(S + SA1_OFF + i0 * SA1_STR + 4 * q)      = elu_cvt4(c0);
        *(f16x4*)(S + SA1_OFF + i0 * SA1_STR + 16 + 4 * q) = elu_cvt4(c1);
    }
    wave_fence();   // a1 handoff (intra-wave cross-lane)

    // ---- layer 2: 32 -> 16
    {
        f16x8 bf = *(const f16x8*)(S + SA1_OFF + i0 * SA1_STR + q * 8);
        f32x4 c = b2v;
        c = MFMA(w2h, bf, c); c = MFMA(w2l, bf, c);
        *(f16x4*)(S + SA2_OFF + i0 * SA2_STR + 4 * q) = elu_cvt4(c);
    }
    wave_fence();   // a2 handoff

    // ---- layer 3: 16 -> 8 (K valid for q<2)
    {
        f16x8 bf = *(const f16x8*)(S + SA2_OFF + i0 * SA2_STR + (q & 1) * 8);
        if (q >= 2) bf = (f16x8){};
        f32x4 c = (q < 2) ? b3v : z4;
        c = MFMA(w3h, bf, c); c = MFMA(w3l, bf, c);
        if (q < 2) *(f16x4*)(S + SA3_OFF + i0 * SA3_STR + 4 * q) = elu_cvt4(c);
    }
    wave_fence();   // a3 handoff

    // ---- layer 4 (8->4) + head (4->3): a4 stays in registers
    f32x4 cy;
    {
        f16x8 bf = *(const f16x8*)(S + SA3_OFF + i0 * SA3_STR);
        if (q != 0) bf = (f16x8){};
        f32x4 c = (q == 0) ? b4v : z4;
        c = MFMA(w4h, bf, c); c = MFMA(w4l, bf, c);

        f16x8 h = (f16x8){};
        if (q == 0) {
#pragma unroll
            for (int e = 0; e < 4; ++e) h[e] = (f16)eluf(c[e]);
        }
        cy = z4;
        if (q == 0) { cy[0] = cb0v; cy[1] = cb1v; cy[2] = cb2v; }
        cy = MFMA(whh, h, cy); cy = MFMA(whl, h, cy);
    }

    // ---- epilogue: y via shuffle from the q==0 lane of column p ----
    {
        float y0 = __shfl(cy[0], p);
        float y1 = __shfl(cy[1], p);
        float y2 = __shfl(cy[2], p);

        float theta = 0.5235987756f * fast_sigmoid(y0);   // pi/6
        float phi   = 6.2831853072f * fast_sigmoid(y1);   // 2*pi
        float dist  = 83.0f         * fast_sigmoid(y2);
        float st = __sinf(theta), ct = __cosf(theta);
        float sp = __sinf(phi),   cp = __cosf(phi);
        float n1 = st * cp, n2 = st * sp, n3 = ct;
        float inv = __frsqrt_rn(fmaf(n1, n1, fmaf(n2, n2, n3 * n3)));
        n1 *= inv; n2 *= inv; n3 *= inv;

        const float ksc = 1.0f / (8.0f * 715.0f);
        float nu[8];
#pragma unroll
        for (int j = 0; j < 8; ++j) nu[j] = n1 * (((float)j - 3.5f) * ksc);

        int pix = pixbase + i0;
        int bb  = pix / HW_;
        int hw  = pix - bb * HW_;
        int hh  = hw / W_;
        int ww  = hw - hh * W_;
        const int obase = bb * OHW_ + (hh * 8) * OW_ + ww * 8;
#pragma unroll
        for (int r = 0; r < 2; ++r) {
            int irow = q * 2 + r;               // lane (p,q) writes rows 2q,2q+1
            float base = fmaf(n2, ((float)irow - 3.5f) * ksc, n3);
            float4 r0, r1;
            r0.x = dist * __builtin_amdgcn_rcpf(base + nu[0]);
            r0.y = dist * __builtin_amdgcn_rcpf(base + nu[1]);
            r0.z = dist * __builtin_amdgcn_rcpf(base + nu[2]);
            r0.w = dist * __builtin_amdgcn_rcpf(base + nu[3]);
            r1.x = dist * __builtin_amdgcn_rcpf(base + nu[4]);
            r1.y = dist * __builtin_amdgcn_rcpf(base + nu[5]);
            r1.z = dist * __builtin_amdgcn_rcpf(base + nu[6]);
            r1.w = dist * __builtin_amdgcn_rcpf(base + nu[7]);
            float4* op = (float4*)(out + obase + irow * OW_);
            op[0] = r0;
            op[1] = r1;
        }
    }
}

extern "C" void kernel_launch(void* const* d_in, const int* in_sizes, int n_in,
                              void* d_out, int out_size, void* d_ws, size_t ws_size,
                              hipStream_t stream) {
    const float* x  = (const float*)d_in[0];
    const float* w0 = (const float*)d_in[1];
    const float* b0 = (const float*)d_in[2];
    const float* w1 = (const float*)d_in[3];
    const float* b1 = (const float*)d_in[4];
    const float* w2 = (const float*)d_in[5];
    const float* b2 = (const float*)d_in[6];
    const float* w3 = (const float*)d_in[7];
    const float* b3 = (const float*)d_in[8];
    const float* w4 = (const float*)d_in[9];
    const float* b4 = (const float*)d_in[10];
    const float* cw = (const float*)d_in[11];
    const float* cb = (const float*)d_in[12];
    float* outp = (float*)d_out;

    lpg_mfma<<<NPIX / 64, 256, 0, stream>>>(x, w0, b0, w1, b1, w2, b2, w3, b3,
                                            w4, b4, cw, cb, outp);
}

// Round 17
// 31.008 us; speedup vs baseline: 1.5027x; 1.2723x over previous
//
#include <hip/hip_runtime.h>
#include <math.h>

#define HW_   6688      // 44*152
#define W_    152
#define NPIX  107008    // 16*44*152
#define OW_   1216      // 152*8
#define OHW_  428032    // 352*1216

typedef _Float16 f16;
typedef _Float16 f16x2 __attribute__((ext_vector_type(2)));
typedef _Float16 f16x4 __attribute__((ext_vector_type(4)));
typedef _Float16 f16x8 __attribute__((ext_vector_type(8)));
typedef float    f32x4 __attribute__((ext_vector_type(4)));

#define MFMA(a,b,c) __builtin_amdgcn_mfma_f32_16x16x32_f16((a),(b),(c),0,0,0)

// ---- LDS layout (f16 units), 64 pixels/block. x staged in TWO 64-channel
// halves into [64][72]; a1/a2/a3 overlay the x region AFTER the last block
// barrier (x dead; per-wave rows disjoint -> wave fences suffice in phase C).
#define SXH_STR  72             // x-half [64][72] at 0 -> 4608 f16
#define SA1_OFF  0              // a1 [64][40] -> 2560
#define SA1_STR  40
#define SA2_OFF  2560           // a2 [64][24] -> ends 4096
#define SA2_STR  24
#define SA3_OFF  4096           // a3 [64][16] -> ends 5120
#define SA3_STR  16
#define SA0_OFF  5120           // a0 [64][72] -> ends 9728
#define SA0_STR  72
#define LDSF16   9728           // 19456 B -> 6 blocks/CU = 114 KB

__device__ __forceinline__ float fast_sigmoid(float v) {
    return __builtin_amdgcn_rcpf(1.0f + __expf(-v));
}
__device__ __forceinline__ float eluf(float v) {
    return v > 0.0f ? v : (__expf(v) - 1.0f);
}
// split fp32 -> fp16 hi + fp16 lo (w ~= hi + lo) — L0 only
__device__ __forceinline__ void split8(const float* v, f16x8& hi, f16x8& lo) {
#pragma unroll
    for (int e = 0; e < 8; ++e) {
        f16 h = (f16)v[e];
        hi[e] = h;
        lo[e] = (f16)(v[e] - (float)h);
    }
}
// hi-only RTN conversion (phase-C weights, JIT)
__device__ __forceinline__ f16x8 cvt8h(const float* v) {
    f16x8 r;
#pragma unroll
    for (int e = 0; e < 8; ++e) r[e] = (f16)v[e];
    return r;
}
__device__ __forceinline__ f16x4 elu_cvt4(f32x4 a) {
    f16x4 r;
    r[0] = (f16)eluf(a[0]); r[1] = (f16)eluf(a[1]);
    r[2] = (f16)eluf(a[2]); r[3] = (f16)eluf(a[3]);
    return r;
}
// Intra-wave LDS handoff fence (cross-wave safety = disjoint rows/regions).
__device__ __forceinline__ void wave_fence() {
    __builtin_amdgcn_sched_barrier(0);
    __builtin_amdgcn_wave_barrier();
    __builtin_amdgcn_sched_barrier(0);
}

// 256 threads = 4 waves, 64 pixels/block, 6 blocks/CU (24 waves/CU).
// VGPR demand cut vs r16: phase-C weights are hi-only f16, loaded JUST IN
// TIME inside each layer (short live ranges; no always-live 64-VGPR frag
// block), biases JIT'd likewise. L0 keeps hi+lo split weights.
__global__ __launch_bounds__(256, 6)
void lpg_mfma(const float* __restrict__ x,
              const float* __restrict__ w0, const float* __restrict__ b0,
              const float* __restrict__ w1, const float* __restrict__ b1,
              const float* __restrict__ w2, const float* __restrict__ b2,
              const float* __restrict__ w3, const float* __restrict__ b3,
              const float* __restrict__ w4, const float* __restrict__ b4,
              const float* __restrict__ cw, const float* __restrict__ cb,
              float* __restrict__ out) {
    __shared__ __align__(16) f16 S[LDSF16];

    const int tid  = threadIdx.x;
    const int wv   = __builtin_amdgcn_readfirstlane(tid >> 6);
    const int lane = tid & 63;
    const int p    = lane & 15;   // MFMA row/col index
    const int q    = lane >> 4;   // k-group / C-row group
    const int pixbase = blockIdx.x * 64;

    // staging: thread (i = tid&63) stages pixel i, 16 channels per half
    const int i    = tid & 63;
    const int csub = (tid >> 6) * 16;          // 0..48 within the 64-ch half
    int pixs = pixbase + i;
    int bbs  = pixs / HW_;
    int hws  = pixs - bbs * HW_;
    const float* xps = x + ((size_t)bbs * 128 + csub) * HW_ + hws;
    f16* dsts = S + i * SXH_STR + csub;

    // ---- stage half 0 (channels 0..63): coalesced 256B wave requests
#pragma unroll 8
    for (int k = 0; k < 16; k += 2) {
        float v0 = xps[(size_t)k * HW_];
        float v1 = xps[(size_t)(k + 1) * HW_];
        auto pk = __builtin_amdgcn_cvt_pkrtz(v0, v1);
        f16x2 h; h[0] = (f16)pk[0]; h[1] = (f16)pk[1];
        *(f16x2*)(dsts + k) = h;
    }

    // ---- layer-0 weights for k-half 0 + bias; accs for 4 pixel tiles
    const int w0row = (wv * 16 + p) * 128 + q * 8;
    f16x8 w0h[2], w0l[2];
#pragma unroll
    for (int kt = 0; kt < 2; ++kt) {
        float v[8];
#pragma unroll
        for (int e = 0; e < 8; ++e) v[e] = w0[w0row + kt * 32 + e];
        split8(v, w0h[kt], w0l[kt]);
    }
    f32x4 acc[4];
    {
        f32x4 b0v = *(const f32x4*)(b0 + wv * 16 + 4 * q);
#pragma unroll
        for (int t = 0; t < 4; ++t) acc[t] = b0v;
    }
    __syncthreads();   // (1) half 0 staged

#pragma unroll 2
    for (int t = 0; t < 4; ++t) {
        const f16* bp = S + (t * 16 + p) * SXH_STR + q * 8;
        f16x8 bf0 = *(const f16x8*)(bp);
        f16x8 bf1 = *(const f16x8*)(bp + 32);
        acc[t] = MFMA(w0h[0], bf0, acc[t]); acc[t] = MFMA(w0l[0], bf0, acc[t]);
        acc[t] = MFMA(w0h[1], bf1, acc[t]); acc[t] = MFMA(w0l[1], bf1, acc[t]);
    }
    __syncthreads();   // (2) all waves done reading half 0

    // ---- stage half 1 (channels 64..127) over the same buffer
#pragma unroll 8
    for (int k = 0; k < 16; k += 2) {
        float v0 = xps[(size_t)(k + 64) * HW_];
        float v1 = xps[(size_t)(k + 65) * HW_];
        auto pk = __builtin_amdgcn_cvt_pkrtz(v0, v1);
        f16x2 h; h[0] = (f16)pk[0]; h[1] = (f16)pk[1];
        *(f16x2*)(dsts + k) = h;
    }
#pragma unroll
    for (int kt = 0; kt < 2; ++kt) {     // w0 k-half 1 (reuses registers)
        float v[8];
#pragma unroll
        for (int e = 0; e < 8; ++e) v[e] = w0[w0row + 64 + kt * 32 + e];
        split8(v, w0h[kt], w0l[kt]);
    }
    __syncthreads();   // (3) half 1 staged

#pragma unroll 2
    for (int t = 0; t < 4; ++t) {
        const f16* bp = S + (t * 16 + p) * SXH_STR + q * 8;
        f16x8 bf0 = *(const f16x8*)(bp);
        f16x8 bf1 = *(const f16x8*)(bp + 32);
        acc[t] = MFMA(w0h[0], bf0, acc[t]); acc[t] = MFMA(w0l[0], bf0, acc[t]);
        acc[t] = MFMA(w0h[1], bf1, acc[t]); acc[t] = MFMA(w0l[1], bf1, acc[t]);
        *(f16x4*)(S + SA0_OFF + (t * 16 + p) * SA0_STR + wv * 16 + 4 * q) = elu_cvt4(acc[t]);
    }
    __syncthreads();   // (4) a0 complete — last block barrier; x region dead

    // ========== phase C: wave-private tile [wv*16,+16), JIT hi-only weights ==========
    const f32x4 z4 = {0.f, 0.f, 0.f, 0.f};
    const int i0 = wv * 16 + p;   // this wave's tile row (block-local pixel)

    // ---- layer 1: 64 -> 32
    {
        f16x8 wf[2][2];
#pragma unroll
        for (int Mt = 0; Mt < 2; ++Mt)
#pragma unroll
            for (int kt = 0; kt < 2; ++kt)
                wf[Mt][kt] = cvt8h(w1 + (Mt * 16 + p) * 64 + kt * 32 + q * 8);
        f32x4 c0 = *(const f32x4*)(b1 + 4 * q);
        f32x4 c1 = *(const f32x4*)(b1 + 16 + 4 * q);
#pragma unroll
        for (int kt = 0; kt < 2; ++kt) {
            f16x8 bf = *(const f16x8*)(S + SA0_OFF + i0 * SA0_STR + kt * 32 + q * 8);
            c0 = MFMA(wf[0][kt], bf, c0);
            c1 = MFMA(wf[1][kt], bf, c1);
        }
        *(f16x4*)(S + SA1_OFF + i0 * SA1_STR + 4 * q)      = elu_cvt4(c0);
        *(f16x4*)(S + SA1_OFF + i0 * SA1_STR + 16 + 4 * q) = elu_cvt4(c1);
    }
    wave_fence();   // a1 handoff (intra-wave cross-lane)

    // ---- layer 2: 32 -> 16
    {
        f16x8 wf = cvt8h(w2 + p * 32 + q * 8);
        f16x8 bf = *(const f16x8*)(S + SA1_OFF + i0 * SA1_STR + q * 8);
        f32x4 c = *(const f32x4*)(b2 + 4 * q);
        c = MFMA(wf, bf, c);
        *(f16x4*)(S + SA2_OFF + i0 * SA2_STR + 4 * q) = elu_cvt4(c);
    }
    wave_fence();   // a2 handoff

    // ---- layer 3: 16 -> 8 (A-frag zero-padded outside 8x16 -> no B mask)
    {
        f16x8 wf = (f16x8){};
        if (p < 8 && q < 2) wf = cvt8h(w3 + p * 16 + q * 8);
        f16x8 bf = *(const f16x8*)(S + SA2_OFF + i0 * SA2_STR + (q & 1) * 8);
        f32x4 c = (q < 2) ? *(const f32x4*)(b3 + 4 * q) : z4;
        c = MFMA(wf, bf, c);
        if (q < 2) *(f16x4*)(S + SA3_OFF + i0 * SA3_STR + 4 * q) = elu_cvt4(c);
    }
    wave_fence();   // a3 handoff

    // ---- layer 4 (8->4) + head (4->3): a4 stays in registers
    f32x4 cy;
    {
        f16x8 wf = (f16x8){};
        if (p < 4 && q == 0) wf = cvt8h(w4 + p * 8);
        f16x8 bf = *(const f16x8*)(S + SA3_OFF + i0 * SA3_STR);
        f32x4 c = (q == 0) ? *(const f32x4*)(b4) : z4;
        c = MFMA(wf, bf, c);

        f16x8 hh = (f16x8){};
        if (q == 0) {
#pragma unroll
            for (int e = 0; e < 4; ++e) hh[e] = (f16)eluf(c[e]);
        }
        f16x8 wh = (f16x8){};
        if (p < 3 && q == 0) {
#pragma unroll
            for (int e = 0; e < 4; ++e) wh[e] = (f16)cw[p * 4 + e];
        }
        cy = z4;
        if (q == 0) { cy[0] = cb[0]; cy[1] = cb[1]; cy[2] = cb[2]; }
        cy = MFMA(wh, hh, cy);
    }

    // ---- epilogue: y via shuffle from the q==0 lane of column p ----
    {
        float y0 = __shfl(cy[0], p);
        float y1 = __shfl(cy[1], p);
        float y2 = __shfl(cy[2], p);

        float theta = 0.5235987756f * fast_sigmoid(y0);   // pi/6
        float phi   = 6.2831853072f * fast_sigmoid(y1);   // 2*pi
        float dist  = 83.0f         * fast_sigmoid(y2);
        float st = __sinf(theta), ct = __cosf(theta);
        float sp = __sinf(phi),   cp = __cosf(phi);
        float n1 = st * cp, n2 = st * sp, n3 = ct;
        float inv = __frsqrt_rn(fmaf(n1, n1, fmaf(n2, n2, n3 * n3)));
        n1 *= inv; n2 *= inv; n3 *= inv;

        const float ksc = 1.0f / (8.0f * 715.0f);
        float nu[8];
#pragma unroll
        for (int j = 0; j < 8; ++j) nu[j] = n1 * (((float)j - 3.5f) * ksc);

        int pix = pixbase + i0;
        int bb  = pix / HW_;
        int hw  = pix - bb * HW_;
        int hh  = hw / W_;
        int ww  = hw - hh * W_;
        const int obase = bb * OHW_ + (hh * 8) * OW_ + ww * 8;
#pragma unroll
        for (int r = 0; r < 2; ++r) {
            int irow = q * 2 + r;               // lane (p,q) writes rows 2q,2q+1
            float base = fmaf(n2, ((float)irow - 3.5f) * ksc, n3);
            float4 r0, r1;
            r0.x = dist * __builtin_amdgcn_rcpf(base + nu[0]);
            r0.y = dist * __builtin_amdgcn_rcpf(base + nu[1]);
            r0.z = dist * __builtin_amdgcn_rcpf(base + nu[2]);
            r0.w = dist * __builtin_amdgcn_rcpf(base + nu[3]);
            r1.x = dist * __builtin_amdgcn_rcpf(base + nu[4]);
            r1.y = dist * __builtin_amdgcn_rcpf(base + nu[5]);
            r1.z = dist * __builtin_amdgcn_rcpf(base + nu[6]);
            r1.w = dist * __builtin_amdgcn_rcpf(base + nu[7]);
            float4* op = (float4*)(out + obase + irow * OW_);
            op[0] = r0;
            op[1] = r1;
        }
    }
}

extern "C" void kernel_launch(void* const* d_in, const int* in_sizes, int n_in,
                              void* d_out, int out_size, void* d_ws, size_t ws_size,
                              hipStream_t stream) {
    const float* x  = (const float*)d_in[0];
    const float* w0 = (const float*)d_in[1];
    const float* b0 = (const float*)d_in[2];
    const float* w1 = (const float*)d_in[3];
    const float* b1 = (const float*)d_in[4];
    const float* w2 = (const float*)d_in[5];
    const float* b2 = (const float*)d_in[6];
    const float* w3 = (const float*)d_in[7];
    const float* b3 = (const float*)d_in[8];
    const float* w4 = (const float*)d_in[9];
    const float* b4 = (const float*)d_in[10];
    const float* cw = (const float*)d_in[11];
    const float* cb = (const float*)d_in[12];
    float* outp = (float*)d_out;

    lpg_mfma<<<NPIX / 64, 256, 0, stream>>>(x, w0, b0, w1, b1, w2, b2, w3, b3,
                                            w4, b4, cw, cb, outp);
}

// Round 18
// 30.863 us; speedup vs baseline: 1.5098x; 1.0047x over previous
//
#include <hip/hip_runtime.h>
#include <math.h>

#define HW_   6688      // 44*152
#define W_    152
#define NPIX  107008    // 16*44*152
#define OW_   1216      // 152*8
#define OHW_  428032    // 352*1216

typedef _Float16 f16;
typedef _Float16 f16x2 __attribute__((ext_vector_type(2)));
typedef _Float16 f16x4 __attribute__((ext_vector_type(4)));
typedef _Float16 f16x8 __attribute__((ext_vector_type(8)));
typedef float    f32x4 __attribute__((ext_vector_type(4)));

#define MFMA(a,b,c) __builtin_amdgcn_mfma_f32_16x16x32_f16((a),(b),(c),0,0,0)

// ---- LDS layout (f16 units), 64 pixels/block. x staged in TWO 64-channel
// halves into [64][72]; a1/a2/a3 overlay the x region AFTER the last block
// barrier (x dead; per-wave rows disjoint -> wave fences suffice in phase C).
#define SXH_STR  72             // x-half [64][72] at 0 -> 4608 f16
#define SA1_OFF  0              // a1 [64][40] -> 2560
#define SA1_STR  40
#define SA2_OFF  2560           // a2 [64][24] -> ends 4096
#define SA2_STR  24
#define SA3_OFF  4096           // a3 [64][16] -> ends 5120
#define SA3_STR  16
#define SA0_OFF  5120           // a0 [64][72] -> ends 9728
#define SA0_STR  72
#define LDSF16   9728           // 19456 B -> 6 blocks/CU = 114 KB

__device__ __forceinline__ float fast_sigmoid(float v) {
    return __builtin_amdgcn_rcpf(1.0f + __expf(-v));
}
__device__ __forceinline__ float eluf(float v) {
    return v > 0.0f ? v : (__expf(v) - 1.0f);
}
// split fp32 -> fp16 hi + fp16 lo (w ~= hi + lo) — L0 only
__device__ __forceinline__ void split8(const float* v, f16x8& hi, f16x8& lo) {
#pragma unroll
    for (int e = 0; e < 8; ++e) {
        f16 h = (f16)v[e];
        hi[e] = h;
        lo[e] = (f16)(v[e] - (float)h);
    }
}
// hi-only RTN conversion (phase-C weights, JIT)
__device__ __forceinline__ f16x8 cvt8h(const float* v) {
    f16x8 r;
#pragma unroll
    for (int e = 0; e < 8; ++e) r[e] = (f16)v[e];
    return r;
}
__device__ __forceinline__ f16x4 elu_cvt4(f32x4 a) {
    f16x4 r;
    r[0] = (f16)eluf(a[0]); r[1] = (f16)eluf(a[1]);
    r[2] = (f16)eluf(a[2]); r[3] = (f16)eluf(a[3]);
    return r;
}
// Intra-wave LDS handoff fence (cross-wave safety = disjoint rows/regions).
__device__ __forceinline__ void wave_fence() {
    __builtin_amdgcn_sched_barrier(0);
    __builtin_amdgcn_wave_barrier();
    __builtin_amdgcn_sched_barrier(0);
}

// 256 threads = 4 waves, 64 pixels/block, 6 blocks/CU (24 waves/CU).
// VGPR demand cut vs r16: phase-C weights are hi-only f16, loaded JUST IN
// TIME inside each layer (short live ranges; no always-live 64-VGPR frag
// block), biases JIT'd likewise. L0 keeps hi+lo split weights.
__global__ __launch_bounds__(256, 6)
void lpg_mfma(const float* __restrict__ x,
              const float* __restrict__ w0, const float* __restrict__ b0,
              const float* __restrict__ w1, const float* __restrict__ b1,
              const float* __restrict__ w2, const float* __restrict__ b2,
              const float* __restrict__ w3, const float* __restrict__ b3,
              const float* __restrict__ w4, const float* __restrict__ b4,
              const float* __restrict__ cw, const float* __restrict__ cb,
              float* __restrict__ out) {
    __shared__ __align__(16) f16 S[LDSF16];

    const int tid  = threadIdx.x;
    const int wv   = __builtin_amdgcn_readfirstlane(tid >> 6);
    const int lane = tid & 63;
    const int p    = lane & 15;   // MFMA row/col index
    const int q    = lane >> 4;   // k-group / C-row group
    const int pixbase = blockIdx.x * 64;

    // staging: thread (i = tid&63) stages pixel i, 16 channels per half
    const int i    = tid & 63;
    const int csub = (tid >> 6) * 16;          // 0..48 within the 64-ch half
    int pixs = pixbase + i;
    int bbs  = pixs / HW_;
    int hws  = pixs - bbs * HW_;
    const float* xps = x + ((size_t)bbs * 128 + csub) * HW_ + hws;
    f16* dsts = S + i * SXH_STR + csub;

    // ---- stage half 0 (channels 0..63): coalesced 256B wave requests
#pragma unroll 8
    for (int k = 0; k < 16; k += 2) {
        float v0 = xps[(size_t)k * HW_];
        float v1 = xps[(size_t)(k + 1) * HW_];
        auto pk = __builtin_amdgcn_cvt_pkrtz(v0, v1);
        f16x2 h; h[0] = (f16)pk[0]; h[1] = (f16)pk[1];
        *(f16x2*)(dsts + k) = h;
    }

    // ---- layer-0 weights for k-half 0 + bias; accs for 4 pixel tiles
    const int w0row = (wv * 16 + p) * 128 + q * 8;
    f16x8 w0h[2], w0l[2];
#pragma unroll
    for (int kt = 0; kt < 2; ++kt) {
        float v[8];
#pragma unroll
        for (int e = 0; e < 8; ++e) v[e] = w0[w0row + kt * 32 + e];
        split8(v, w0h[kt], w0l[kt]);
    }
    f32x4 acc[4];
    {
        f32x4 b0v = *(const f32x4*)(b0 + wv * 16 + 4 * q);
#pragma unroll
        for (int t = 0; t < 4; ++t) acc[t] = b0v;
    }
    __syncthreads();   // (1) half 0 staged

#pragma unroll 2
    for (int t = 0; t < 4; ++t) {
        const f16* bp = S + (t * 16 + p) * SXH_STR + q * 8;
        f16x8 bf0 = *(const f16x8*)(bp);
        f16x8 bf1 = *(const f16x8*)(bp + 32);
        acc[t] = MFMA(w0h[0], bf0, acc[t]); acc[t] = MFMA(w0l[0], bf0, acc[t]);
        acc[t] = MFMA(w0h[1], bf1, acc[t]); acc[t] = MFMA(w0l[1], bf1, acc[t]);
    }
    __syncthreads();   // (2) all waves done reading half 0

    // ---- stage half 1 (channels 64..127) over the same buffer
#pragma unroll 8
    for (int k = 0; k < 16; k += 2) {
        float v0 = xps[(size_t)(k + 64) * HW_];
        float v1 = xps[(size_t)(k + 65) * HW_];
        auto pk = __builtin_amdgcn_cvt_pkrtz(v0, v1);
        f16x2 h; h[0] = (f16)pk[0]; h[1] = (f16)pk[1];
        *(f16x2*)(dsts + k) = h;
    }
#pragma unroll
    for (int kt = 0; kt < 2; ++kt) {     // w0 k-half 1 (reuses registers)
        float v[8];
#pragma unroll
        for (int e = 0; e < 8; ++e) v[e] = w0[w0row + 64 + kt * 32 + e];
        split8(v, w0h[kt], w0l[kt]);
    }
    __syncthreads();   // (3) half 1 staged

#pragma unroll 2
    for (int t = 0; t < 4; ++t) {
        const f16* bp = S + (t * 16 + p) * SXH_STR + q * 8;
        f16x8 bf0 = *(const f16x8*)(bp);
        f16x8 bf1 = *(const f16x8*)(bp + 32);
        acc[t] = MFMA(w0h[0], bf0, acc[t]); acc[t] = MFMA(w0l[0], bf0, acc[t]);
        acc[t] = MFMA(w0h[1], bf1, acc[t]); acc[t] = MFMA(w0l[1], bf1, acc[t]);
        *(f16x4*)(S + SA0_OFF + (t * 16 + p) * SA0_STR + wv * 16 + 4 * q) = elu_cvt4(acc[t]);
    }
    __syncthreads();   // (4) a0 complete — last block barrier; x region dead

    // ========== phase C: wave-private tile [wv*16,+16), JIT hi-only weights ==========
    const f32x4 z4 = {0.f, 0.f, 0.f, 0.f};
    const int i0 = wv * 16 + p;   // this wave's tile row (block-local pixel)

    // ---- layer 1: 64 -> 32
    {
        f16x8 wf[2][2];
#pragma unroll
        for (int Mt = 0; Mt < 2; ++Mt)
#pragma unroll
            for (int kt = 0; kt < 2; ++kt)
                wf[Mt][kt] = cvt8h(w1 + (Mt * 16 + p) * 64 + kt * 32 + q * 8);
        f32x4 c0 = *(const f32x4*)(b1 + 4 * q);
        f32x4 c1 = *(const f32x4*)(b1 + 16 + 4 * q);
#pragma unroll
        for (int kt = 0; kt < 2; ++kt) {
            f16x8 bf = *(const f16x8*)(S + SA0_OFF + i0 * SA0_STR + kt * 32 + q * 8);
            c0 = MFMA(wf[0][kt], bf, c0);
            c1 = MFMA(wf[1][kt], bf, c1);
        }
        *(f16x4*)(S + SA1_OFF + i0 * SA1_STR + 4 * q)      = elu_cvt4(c0);
        *(f16x4*)(S + SA1_OFF + i0 * SA1_STR + 16 + 4 * q) = elu_cvt4(c1);
    }
    wave_fence();   // a1 handoff (intra-wave cross-lane)

    // ---- layer 2: 32 -> 16
    {
        f16x8 wf = cvt8h(w2 + p * 32 + q * 8);
        f16x8 bf = *(const f16x8*)(S + SA1_OFF + i0 * SA1_STR + q * 8);
        f32x4 c = *(const f32x4*)(b2 + 4 * q);
        c = MFMA(wf, bf, c);
        *(f16x4*)(S + SA2_OFF + i0 * SA2_STR + 4 * q) = elu_cvt4(c);
    }
    wave_fence();   // a2 handoff

    // ---- layer 3: 16 -> 8 (A-frag zero-padded outside 8x16 -> no B mask)
    {
        f16x8 wf = (f16x8){};
        if (p < 8 && q < 2) wf = cvt8h(w3 + p * 16 + q * 8);
        f16x8 bf = *(const f16x8*)(S + SA2_OFF + i0 * SA2_STR + (q & 1) * 8);
        f32x4 c = (q < 2) ? *(const f32x4*)(b3 + 4 * q) : z4;
        c = MFMA(wf, bf, c);
        if (q < 2) *(f16x4*)(S + SA3_OFF + i0 * SA3_STR + 4 * q) = elu_cvt4(c);
    }
    wave_fence();   // a3 handoff

    // ---- layer 4 (8->4) + head (4->3): a4 stays in registers
    f32x4 cy;
    {
        f16x8 wf = (f16x8){};
        if (p < 4 && q == 0) wf = cvt8h(w4 + p * 8);
        f16x8 bf = *(const f16x8*)(S + SA3_OFF + i0 * SA3_STR);
        f32x4 c = (q == 0) ? *(const f32x4*)(b4) : z4;
        c = MFMA(wf, bf, c);

        f16x8 hh = (f16x8){};
        if (q == 0) {
#pragma unroll
            for (int e = 0; e < 4; ++e) hh[e] = (f16)eluf(c[e]);
        }
        f16x8 wh = (f16x8){};
        if (p < 3 && q == 0) {
#pragma unroll
            for (int e = 0; e < 4; ++e) wh[e] = (f16)cw[p * 4 + e];
        }
        cy = z4;
        if (q == 0) { cy[0] = cb[0]; cy[1] = cb[1]; cy[2] = cb[2]; }
        cy = MFMA(wh, hh, cy);
    }

    // ---- epilogue: y via shuffle from the q==0 lane of column p ----
    {
        float y0 = __shfl(cy[0], p);
        float y1 = __shfl(cy[1], p);
        float y2 = __shfl(cy[2], p);

        float theta = 0.5235987756f * fast_sigmoid(y0);   // pi/6
        float phi   = 6.2831853072f * fast_sigmoid(y1);   // 2*pi
        float dist  = 83.0f         * fast_sigmoid(y2);
        float st = __sinf(theta), ct = __cosf(theta);
        float sp = __sinf(phi),   cp = __cosf(phi);
        float n1 = st * cp, n2 = st * sp, n3 = ct;
        float inv = __frsqrt_rn(fmaf(n1, n1, fmaf(n2, n2, n3 * n3)));
        n1 *= inv; n2 *= inv; n3 *= inv;

        const float ksc = 1.0f / (8.0f * 715.0f);
        float nu[8];
#pragma unroll
        for (int j = 0; j < 8; ++j) nu[j] = n1 * (((float)j - 3.5f) * ksc);

        int pix = pixbase + i0;
        int bb  = pix / HW_;
        int hw  = pix - bb * HW_;
        int hh  = hw / W_;
        int ww  = hw - hh * W_;
        const int obase = bb * OHW_ + (hh * 8) * OW_ + ww * 8;
#pragma unroll
        for (int r = 0; r < 2; ++r) {
            int irow = q * 2 + r;               // lane (p,q) writes rows 2q,2q+1
            float base = fmaf(n2, ((float)irow - 3.5f) * ksc, n3);
            float4 r0, r1;
            r0.x = dist * __builtin_amdgcn_rcpf(base + nu[0]);
            r0.y = dist * __builtin_amdgcn_rcpf(base + nu[1]);
            r0.z = dist * __builtin_amdgcn_rcpf(base + nu[2]);
            r0.w = dist * __builtin_amdgcn_rcpf(base + nu[3]);
            r1.x = dist * __builtin_amdgcn_rcpf(base + nu[4]);
            r1.y = dist * __builtin_amdgcn_rcpf(base + nu[5]);
            r1.z = dist * __builtin_amdgcn_rcpf(base + nu[6]);
            r1.w = dist * __builtin_amdgcn_rcpf(base + nu[7]);
            float4* op = (float4*)(out + obase + irow * OW_);
            op[0] = r0;
            op[1] = r1;
        }
    }
}

extern "C" void kernel_launch(void* const* d_in, const int* in_sizes, int n_in,
                              void* d_out, int out_size, void* d_ws, size_t ws_size,
                              hipStream_t stream) {
    const float* x  = (const float*)d_in[0];
    const float* w0 = (const float*)d_in[1];
    const float* b0 = (const float*)d_in[2];
    const float* w1 = (const float*)d_in[3];
    const float* b1 = (const float*)d_in[4];
    const float* w2 = (const float*)d_in[5];
    const float* b2 = (const float*)d_in[6];
    const float* w3 = (const float*)d_in[7];
    const float* b3 = (const float*)d_in[8];
    const float* w4 = (const float*)d_in[9];
    const float* b4 = (const float*)d_in[10];
    const float* cw = (const float*)d_in[11];
    const float* cb = (const float*)d_in[12];
    float* outp = (float*)d_out;

    lpg_mfma<<<NPIX / 64, 256, 0, stream>>>(x, w0, b0, w1, b1, w2, b2, w3, b3,
                                            w4, b4, cw, cb, outp);
}